// Round 1
// baseline (373.488 us; speedup 1.0000x reference)
//
#include <hip/hip_runtime.h>
#include <math.h>

#define N_NODES 50000
#define N_EDGES 800000
#define DIM 256
#define HEADS 8
#define DIM_OUT 32
#define INNER 256        // HEADS*DIM_OUT
#define M_PAD 50048      // 391 * 128

typedef __attribute__((ext_vector_type(8))) short bf16x8;
typedef __attribute__((ext_vector_type(4))) float f32x4;
typedef __attribute__((ext_vector_type(2))) float f32x2;

// round-to-nearest-even f32 -> bf16 bits
__device__ __forceinline__ unsigned short f2bf(float f) {
    unsigned u = __float_as_uint(f);
    unsigned r = (u + 0x7FFFu + ((u >> 16) & 1u)) >> 16;
    return (unsigned short)r;
}

// unpack uint (2 packed bf16) -> f32x2
__device__ __forceinline__ f32x2 up2(unsigned u) {
    f32x2 r;
    r.x = __uint_as_float(u << 16);
    r.y = __uint_as_float(u & 0xFFFF0000u);
    return r;
}
__device__ __forceinline__ void up2x4(uint4 r, f32x2* o) {
    o[0] = up2(r.x); o[1] = up2(r.y); o[2] = up2(r.z); o[3] = up2(r.w);
}

// global -> LDS direct copy, 16 B per lane, dest = wave-uniform base + lane*16
__device__ __forceinline__ void gll16(const void* g, void* l) {
    __builtin_amdgcn_global_load_lds(
        (const __attribute__((address_space(1))) unsigned*)(uintptr_t)g,
        (__attribute__((address_space(3))) unsigned*)(unsigned)(uintptr_t)l,
        16, 0, 0);
}

// ---------------------------------------------------------------------------
// prep: conv_x (6256 blocks) + conv_w (768) + deg_hist (3125), one dispatch.
// ---------------------------------------------------------------------------
#define NB_CONVX 6256   // M_PAD*256/8/256
#define NB_CONVW 768    // 3*65536/256
#define NB_HIST  3125   // N_EDGES/256
__global__ __launch_bounds__(256) void prep(
    const float* __restrict__ x,
    const float* __restrict__ Wq, const float* __restrict__ Wk,
    const float* __restrict__ Wv,
    const int* __restrict__ dst,
    unsigned short* __restrict__ xbf, unsigned short* __restrict__ Wt,
    int* __restrict__ deg)
{
    int b = blockIdx.x;
    if (b < NB_CONVX) {
        size_t i8 = ((size_t)b * 256 + threadIdx.x) * 8;
        unsigned short h[8];
        if (i8 < (size_t)N_NODES * 256) {
            float4 a = *(const float4*)(x + i8);
            float4 c = *(const float4*)(x + i8 + 4);
            h[0]=f2bf(a.x); h[1]=f2bf(a.y); h[2]=f2bf(a.z); h[3]=f2bf(a.w);
            h[4]=f2bf(c.x); h[5]=f2bf(c.y); h[6]=f2bf(c.z); h[7]=f2bf(c.w);
        } else {
            #pragma unroll
            for (int j = 0; j < 8; j++) h[j] = 0;
        }
        uint4 o;
        o.x = (unsigned)h[0] | ((unsigned)h[1] << 16);
        o.y = (unsigned)h[2] | ((unsigned)h[3] << 16);
        o.z = (unsigned)h[4] | ((unsigned)h[5] << 16);
        o.w = (unsigned)h[6] | ((unsigned)h[7] << 16);
        *(uint4*)(xbf + i8) = o;
    } else if (b < NB_CONVX + NB_CONVW) {
        int idx = (b - NB_CONVX) * 256 + threadIdx.x;   // < 3*65536
        int z = idx >> 16, r = idx & 65535;
        int k = r >> 8, n = r & 255;
        const float* W = (z == 0) ? Wq : (z == 1) ? Wk : Wv;
        Wt[(size_t)z * 65536 + n * 256 + k] = f2bf(W[k * 256 + n]);
    } else {
        int e = (b - NB_CONVX - NB_CONVW) * 256 + threadIdx.x;
        if (e < N_EDGES) atomicAdd(deg + dst[e], 1);
    }
}

// ---------------------------------------------------------------------------
// Fused QKV GEMM: bf16 MFMA 16x16x32, 128x128 tile, m97-style staging via
// global_load_lds (width 16). LDS rows stride 32 shorts (64 B), unpadded
// (global_load_lds dest is wave-uniform base + lane*16 — no padding allowed).
// ---------------------------------------------------------------------------
__global__ __launch_bounds__(256) void gemm_qkv(
    const unsigned short* __restrict__ xbf,
    const unsigned short* __restrict__ Wt,   // [3][n][k] bf16
    const float* __restrict__ bq, const float* __restrict__ bk,
    const float* __restrict__ bv,
    unsigned short* __restrict__ q, unsigned short* __restrict__ k,
    unsigned short* __restrict__ v)
{
    const int t = threadIdx.x;
    const int row0 = blockIdx.x * 128;
    const int col0 = blockIdx.y * 128;
    const int z = blockIdx.z;
    const unsigned short* Wz = Wt + (size_t)z * 65536;
    const float* bias = (z == 0) ? bq : (z == 1) ? bk : bv;
    unsigned short* C = (z == 0) ? q : (z == 1) ? k : v;

    __shared__ __align__(16) short As[128 * 32];
    __shared__ __align__(16) short Bs[128 * 32];

    const int wave = t >> 6;
    const int lane = t & 63;
    const int wm = (wave & 1) * 64;
    const int wn = (wave >> 1) * 64;
    const int lr = lane & 15;
    const int lg = lane >> 4;
    const int srow = lane >> 2;       // staging: row within 16-row segment
    const int sch  = lane & 3;        // staging: 16-B chunk within row

    f32x4 acc[4][4] = {};

    for (int k0 = 0; k0 < 256; k0 += 32) {
        // A: 128 rows x 32 k; 8 segments of 16 rows; wave w does segs 2w,2w+1
        #pragma unroll
        for (int c = 0; c < 2; c++) {
            int seg = wave * 2 + c;
            gll16(xbf + (size_t)(row0 + seg * 16 + srow) * 256 + k0 + sch * 8,
                  As + seg * 512);      // 512 shorts = 16 rows * 32
        }
        #pragma unroll
        for (int c = 0; c < 2; c++) {
            int seg = wave * 2 + c;
            gll16(Wz + (size_t)(col0 + seg * 16 + srow) * 256 + k0 + sch * 8,
                  Bs + seg * 512);
        }
        __syncthreads();   // compiler emits vmcnt(0) drain before s_barrier

        bf16x8 af[4], bfr[4];
        #pragma unroll
        for (int mi = 0; mi < 4; mi++)
            af[mi] = *(const bf16x8*)&As[(wm + mi * 16 + lr) * 32 + lg * 8];
        #pragma unroll
        for (int ni = 0; ni < 4; ni++)
            bfr[ni] = *(const bf16x8*)&Bs[(wn + ni * 16 + lr) * 32 + lg * 8];
        #pragma unroll
        for (int mi = 0; mi < 4; mi++)
            #pragma unroll
            for (int ni = 0; ni < 4; ni++)
                acc[mi][ni] = __builtin_amdgcn_mfma_f32_16x16x32_bf16(
                    af[mi], bfr[ni], acc[mi][ni], 0, 0, 0);
        __syncthreads();
    }

    // epilogue: C/D layout col=lane&15, row=(lane>>4)*4+reg  [m89-verified]
    #pragma unroll
    for (int mi = 0; mi < 4; mi++) {
        #pragma unroll
        for (int ni = 0; ni < 4; ni++) {
            int gcol = col0 + wn + ni * 16 + lr;
            float bb = bias[gcol];
            #pragma unroll
            for (int r = 0; r < 4; r++) {
                int grow = row0 + wm + mi * 16 + lg * 4 + r;
                if (grow < N_NODES)
                    C[(size_t)grow * 256 + gcol] = f2bf(acc[mi][ni][r] + bb);
            }
        }
    }
}

// ---------------------------------------------------------------------------
// Single-block scan, wave-shuffle version: 3 barriers/tile instead of ~22.
// 1024 threads = 16 waves; each thread owns int4 (4096 ints per tile).
// ---------------------------------------------------------------------------
__global__ __launch_bounds__(1024) void scan_deg(
    const int* __restrict__ deg, int* __restrict__ rowptr)
{
    __shared__ int wsum[16];
    __shared__ int wpre[16];
    int t = threadIdx.x;
    int wid = t >> 6, ln = t & 63;
    int carry = 0;
    for (int base = 0; base < N_NODES; base += 4096) {
        int i4 = base + t * 4;
        int4 dv = {0, 0, 0, 0};
        if (i4 < N_NODES) dv = *(const int4*)(deg + i4);  // N_NODES%4==0
        int sum = dv.x + dv.y + dv.z + dv.w;
        // inclusive wave scan (no barriers)
        int inc = sum;
        #pragma unroll
        for (int off = 1; off < 64; off <<= 1) {
            int u = __shfl_up(inc, off);
            if (ln >= off) inc += u;
        }
        if (ln == 63) wsum[wid] = inc;
        __syncthreads();                       // (1) wsum visible
        if (wid == 0 && ln < 16) {
            int s = wsum[ln];
            int p = s;
            #pragma unroll
            for (int off = 1; off < 16; off <<= 1) {
                int u = __shfl_up(p, off);
                if (ln >= off) p += u;
            }
            wpre[ln] = p - s;                  // exclusive wave prefix
        }
        __syncthreads();                       // (2) wpre visible
        if (i4 < N_NODES) {
            int r = carry + wpre[wid] + (inc - sum);   // exclusive prefix
            r += dv.x; rowptr[i4 + 1] = r;
            r += dv.y; rowptr[i4 + 2] = r;
            r += dv.z; rowptr[i4 + 3] = r;
            r += dv.w; rowptr[i4 + 4] = r;
        }
        carry += wpre[15] + wsum[15];          // block total
        __syncthreads();                       // (3) protect wsum for next tile
    }
    if (t == 0) rowptr[0] = 0;
}

// csr_scatter consumes deg via atomicSub (deg dead after scan).
// Payload is src[e] directly — node_attn then needs NO src[] indirection.
__global__ __launch_bounds__(256) void csr_scatter(
    const int* __restrict__ src, const int* __restrict__ dst,
    const int* __restrict__ rowptr,
    int* __restrict__ deg, int* __restrict__ edge_src)
{
    int e = blockIdx.x * 256 + threadIdx.x;
    if (e >= N_EDGES) return;
    int d = dst[e];
    int old = atomicSub(deg + d, 1);      // old in [1..degree]
    edge_src[rowptr[d] + old - 1] = src[e];
}

// ---------------------------------------------------------------------------
// Fused single-pass attention per dst node. One wave per node, half-wave per
// edge stream (32 lanes x 8 bf16 = 256 dims). Flash-style online softmax.
// CSR payload is src id directly: dependent chain is edge_src[i] -> q/v row
// (2 levels, was 3). Prefetch: src ids 3 ahead, q/v rows 2 ahead.
// Lane l in [0,32): dims [8l,8l+8), head h = l>>2.
// ---------------------------------------------------------------------------
__global__ __launch_bounds__(256) void node_attn(
    const unsigned short* __restrict__ qbf,
    const unsigned short* __restrict__ kbf,
    const unsigned short* __restrict__ vbf,
    const int* __restrict__ rowptr, const int* __restrict__ edge_src,
    float* __restrict__ out)
{
    int node = blockIdx.x * 4 + (threadIdx.x >> 6);
    int lane = threadIdx.x & 63;
    if (node >= N_NODES) return;
    const int half = lane >> 5;
    const int l = lane & 31;

    f32x2 kf2[4];
    up2x4(*(const uint4*)(kbf + (size_t)node * 256 + l * 8), kf2);

    int beg = rowptr[node], end = rowptr[node + 1];

    float m = -INFINITY, zsum = 0.0f;
    f32x2 af2[4] = {};

    int i0 = beg + half;                 // this half's stream, step 2
    bool va0 = i0 < end;
    bool va1 = (i0 + 2) < end;
    bool va2 = (i0 + 4) < end;
    int s0 = va0 ? edge_src[i0] : 0;
    int s1 = va1 ? edge_src[i0 + 2] : 0;
    int s2 = va2 ? edge_src[i0 + 4] : 0;
    uint4 q0 = {}, v0 = {}, q1 = {}, v1 = {};
    if (va0) {
        q0 = *(const uint4*)(qbf + (size_t)s0 * 256 + l * 8);
        v0 = *(const uint4*)(vbf + (size_t)s0 * 256 + l * 8);
    }
    if (va1) {
        q1 = *(const uint4*)(qbf + (size_t)s1 * 256 + l * 8);
        v1 = *(const uint4*)(vbf + (size_t)s1 * 256 + l * 8);
    }
    int ii = i0 + 6;

    while (va0) {
        // issue loads for edge i+2 (s2 known since previous iteration)
        uint4 q2 = {}, v2 = {};
        if (va2) {
            q2 = *(const uint4*)(qbf + (size_t)s2 * 256 + l * 8);
            v2 = *(const uint4*)(vbf + (size_t)s2 * 256 + l * 8);
        }
        // prefetch src id for edge i+3 (single coalesced-segment load)
        bool va3 = ii < end;
        int s3 = va3 ? edge_src[ii] : 0;
        ii += 2;

        // compute with current rows (packed f32x2 -> v_pk_fma_f32)
        f32x2 qf2[4], vf2[4];
        up2x4(q0, qf2);
        up2x4(v0, vf2);
        f32x2 d2 = qf2[0] * kf2[0];
        d2 += qf2[1] * kf2[1];
        d2 += qf2[2] * kf2[2];
        d2 += qf2[3] * kf2[3];
        float t = d2.x + d2.y;
        t += __shfl_xor(t, 1);
        t += __shfl_xor(t, 2);   // 4 lanes of the head group hold the dot
        float sc = t * 0.17677669529663687f;   // 1/sqrt(32)
        float mn = fmaxf(m, sc);
        float alpha = __expf(m - mn);
        float w = __expf(sc - mn);
        zsum = zsum * alpha + w;
        f32x2 a2 = {alpha, alpha};
        f32x2 w2 = {w, w};
        #pragma unroll
        for (int j = 0; j < 4; j++) af2[j] = af2[j] * a2 + vf2[j] * w2;
        m = mn;

        // shift pipeline
        q0 = q1; v0 = v1; q1 = q2; v1 = v2;
        s2 = s3;
        va0 = va1; va1 = va2; va2 = va3;
    }

    // combine halves: rescale to common max, sum across lane^32
    float mo = __shfl_xor(m, 32);
    float mt = fmaxf(m, mo);
    float scale = (m == -INFINITY) ? 0.0f : __expf(m - mt);
    zsum *= scale;
    zsum += __shfl_xor(zsum, 32);
    #pragma unroll
    for (int j = 0; j < 4; j++) {
        af2[j].x = af2[j].x * scale;
        af2[j].y = af2[j].y * scale;
        af2[j].x += __shfl_xor(af2[j].x, 32);
        af2[j].y += __shfl_xor(af2[j].y, 32);
    }

    float inv = 1.0f / fmaxf(zsum, 1e-16f);
    if (half == 0) {
        float4 o0 = {af2[0].x * inv, af2[0].y * inv, af2[1].x * inv, af2[1].y * inv};
        float4 o1 = {af2[2].x * inv, af2[2].y * inv, af2[3].x * inv, af2[3].y * inv};
        float* op = out + (size_t)node * 256 + l * 8;
        *(float4*)op = o0;
        *(float4*)(op + 4) = o1;
    }
}

// ---------------------------------------------------------------------------
extern "C" void kernel_launch(void* const* d_in, const int* in_sizes, int n_in,
                              void* d_out, int out_size, void* d_ws, size_t ws_size,
                              hipStream_t stream) {
    const float* x  = (const float*)d_in[0];
    const float* Wq = (const float*)d_in[1];
    const float* bq = (const float*)d_in[2];
    const float* Wk = (const float*)d_in[3];
    const float* bk = (const float*)d_in[4];
    const float* Wv = (const float*)d_in[5];
    const float* bv = (const float*)d_in[6];
    const int* src  = (const int*)d_in[7];
    const int* dst  = (const int*)d_in[8];
    float* out = (float*)d_out;

    unsigned short* qbf = (unsigned short*)d_ws;
    unsigned short* kbf = qbf + (size_t)N_NODES * INNER;
    unsigned short* vbf = kbf + (size_t)N_NODES * INNER;
    unsigned short* xbf = vbf + (size_t)N_NODES * INNER;
    unsigned short* Wt  = xbf + (size_t)M_PAD * INNER;
    int* deg      = (int*)(Wt + 3 * 65536);
    int* rowptr   = deg + N_NODES;
    int* edge_src = rowptr + (N_NODES + 1);

    hipMemsetAsync(deg, 0, (size_t)N_NODES * sizeof(int), stream);

    prep<<<NB_CONVX + NB_CONVW + NB_HIST, 256, 0, stream>>>(
        x, Wq, Wk, Wv, dst, xbf, Wt, deg);

    dim3 gg(M_PAD / 128, 2, 3);
    gemm_qkv<<<gg, 256, 0, stream>>>(xbf, Wt, bq, bk, bv, qbf, kbf, vbf);

    scan_deg<<<1, 1024, 0, stream>>>(deg, rowptr);
    csr_scatter<<<(N_EDGES + 255) / 256, 256, 0, stream>>>(
        src, dst, rowptr, deg, edge_src);

    node_attn<<<(N_NODES + 3) / 4, 256, 0, stream>>>(
        qbf, kbf, vbf, rowptr, edge_src, out);
}

// Round 2
// 366.592 us; speedup vs baseline: 1.0188x; 1.0188x over previous
//
#include <hip/hip_runtime.h>
#include <math.h>

#define N_NODES 50000
#define N_EDGES 800000
#define DIM 256
#define HEADS 8
#define DIM_OUT 32
#define INNER 256        // HEADS*DIM_OUT
#define M_PAD 50048      // 391 * 128

typedef __attribute__((ext_vector_type(8))) short bf16x8;
typedef __attribute__((ext_vector_type(4))) float f32x4;
typedef __attribute__((ext_vector_type(2))) float f32x2;

// round-to-nearest-even f32 -> bf16 bits
__device__ __forceinline__ unsigned short f2bf(float f) {
    unsigned u = __float_as_uint(f);
    unsigned r = (u + 0x7FFFu + ((u >> 16) & 1u)) >> 16;
    return (unsigned short)r;
}

// unpack uint (2 packed bf16) -> f32x2
__device__ __forceinline__ f32x2 up2(unsigned u) {
    f32x2 r;
    r.x = __uint_as_float(u << 16);
    r.y = __uint_as_float(u & 0xFFFF0000u);
    return r;
}
__device__ __forceinline__ void up2x4(uint4 r, f32x2* o) {
    o[0] = up2(r.x); o[1] = up2(r.y); o[2] = up2(r.z); o[3] = up2(r.w);
}

// global -> LDS direct copy, 16 B per lane, dest = wave-uniform base + lane*16
__device__ __forceinline__ void gll16(const void* g, void* l) {
    __builtin_amdgcn_global_load_lds(
        (const __attribute__((address_space(1))) unsigned*)(uintptr_t)g,
        (__attribute__((address_space(3))) unsigned*)(unsigned)(uintptr_t)l,
        16, 0, 0);
}

// ---------------------------------------------------------------------------
// prep: conv_x (6256 blocks) + conv_w (768) + deg_hist (3125), one dispatch.
// ---------------------------------------------------------------------------
#define NB_CONVX 6256   // M_PAD*256/8/256
#define NB_CONVW 768    // 3*65536/256
#define NB_HIST  3125   // N_EDGES/256
__global__ __launch_bounds__(256) void prep(
    const float* __restrict__ x,
    const float* __restrict__ Wq, const float* __restrict__ Wk,
    const float* __restrict__ Wv,
    const int* __restrict__ dst,
    unsigned short* __restrict__ xbf, unsigned short* __restrict__ Wt,
    int* __restrict__ deg)
{
    int b = blockIdx.x;
    if (b < NB_CONVX) {
        size_t i8 = ((size_t)b * 256 + threadIdx.x) * 8;
        unsigned short h[8];
        if (i8 < (size_t)N_NODES * 256) {
            float4 a = *(const float4*)(x + i8);
            float4 c = *(const float4*)(x + i8 + 4);
            h[0]=f2bf(a.x); h[1]=f2bf(a.y); h[2]=f2bf(a.z); h[3]=f2bf(a.w);
            h[4]=f2bf(c.x); h[5]=f2bf(c.y); h[6]=f2bf(c.z); h[7]=f2bf(c.w);
        } else {
            #pragma unroll
            for (int j = 0; j < 8; j++) h[j] = 0;
        }
        uint4 o;
        o.x = (unsigned)h[0] | ((unsigned)h[1] << 16);
        o.y = (unsigned)h[2] | ((unsigned)h[3] << 16);
        o.z = (unsigned)h[4] | ((unsigned)h[5] << 16);
        o.w = (unsigned)h[6] | ((unsigned)h[7] << 16);
        *(uint4*)(xbf + i8) = o;
    } else if (b < NB_CONVX + NB_CONVW) {
        int idx = (b - NB_CONVX) * 256 + threadIdx.x;   // < 3*65536
        int z = idx >> 16, r = idx & 65535;
        int k = r >> 8, n = r & 255;
        const float* W = (z == 0) ? Wq : (z == 1) ? Wk : Wv;
        Wt[(size_t)z * 65536 + n * 256 + k] = f2bf(W[k * 256 + n]);
    } else {
        int e = (b - NB_CONVX - NB_CONVW) * 256 + threadIdx.x;
        if (e < N_EDGES) atomicAdd(deg + dst[e], 1);
    }
}

// ---------------------------------------------------------------------------
// Fused QKV GEMM: bf16 MFMA 16x16x32, 128x128 tile, m97-style staging via
// global_load_lds (width 16). 1D grid + bijective XCD-chunked swizzle (m204):
// the 6 blocks (y,z) sharing an A row-panel get consecutive logical ids on the
// SAME XCD -> A panel is L2-filled once (~26 MB total) instead of 6x (~154 MB).
// ---------------------------------------------------------------------------
#define GEMM_NWG 2346   // 391 * 2 * 3
__global__ __launch_bounds__(256) void gemm_qkv(
    const unsigned short* __restrict__ xbf,
    const unsigned short* __restrict__ Wt,   // [3][n][k] bf16
    const float* __restrict__ bq, const float* __restrict__ bk,
    const float* __restrict__ bv,
    unsigned short* __restrict__ q, unsigned short* __restrict__ k,
    unsigned short* __restrict__ v)
{
    // XCD-chunked bijective remap (nwg=2346: q8=293, r8=2)
    int hw = blockIdx.x;
    int xcd = hw & 7, pos = hw >> 3;
    const int q8 = GEMM_NWG >> 3, r8 = GEMM_NWG & 7;
    int lid = (xcd < r8 ? xcd * (q8 + 1) : r8 * (q8 + 1) + (xcd - r8) * q8) + pos;
    int xx = lid / 6;               // A row-panel index (slowest)
    int yz = lid - xx * 6;
    const int row0 = xx * 128;
    const int col0 = (yz & 1) * 128;
    const int z = yz >> 1;

    const int t = threadIdx.x;
    const unsigned short* Wz = Wt + (size_t)z * 65536;
    const float* bias = (z == 0) ? bq : (z == 1) ? bk : bv;
    unsigned short* C = (z == 0) ? q : (z == 1) ? k : v;

    __shared__ __align__(16) short As[128 * 32];
    __shared__ __align__(16) short Bs[128 * 32];

    const int wave = t >> 6;
    const int lane = t & 63;
    const int wm = (wave & 1) * 64;
    const int wn = (wave >> 1) * 64;
    const int lr = lane & 15;
    const int lg = lane >> 4;
    const int srow = lane >> 2;       // staging: row within 16-row segment
    const int sch  = lane & 3;        // staging: 16-B chunk within row

    f32x4 acc[4][4] = {};

    for (int k0 = 0; k0 < 256; k0 += 32) {
        #pragma unroll
        for (int c = 0; c < 2; c++) {
            int seg = wave * 2 + c;
            gll16(xbf + (size_t)(row0 + seg * 16 + srow) * 256 + k0 + sch * 8,
                  As + seg * 512);      // 512 shorts = 16 rows * 32
        }
        #pragma unroll
        for (int c = 0; c < 2; c++) {
            int seg = wave * 2 + c;
            gll16(Wz + (size_t)(col0 + seg * 16 + srow) * 256 + k0 + sch * 8,
                  Bs + seg * 512);
        }
        __syncthreads();   // compiler emits vmcnt(0) drain before s_barrier

        bf16x8 af[4], bfr[4];
        #pragma unroll
        for (int mi = 0; mi < 4; mi++)
            af[mi] = *(const bf16x8*)&As[(wm + mi * 16 + lr) * 32 + lg * 8];
        #pragma unroll
        for (int ni = 0; ni < 4; ni++)
            bfr[ni] = *(const bf16x8*)&Bs[(wn + ni * 16 + lr) * 32 + lg * 8];
        #pragma unroll
        for (int mi = 0; mi < 4; mi++)
            #pragma unroll
            for (int ni = 0; ni < 4; ni++)
                acc[mi][ni] = __builtin_amdgcn_mfma_f32_16x16x32_bf16(
                    af[mi], bfr[ni], acc[mi][ni], 0, 0, 0);
        __syncthreads();
    }

    // epilogue: C/D layout col=lane&15, row=(lane>>4)*4+reg  [m89-verified]
    #pragma unroll
    for (int mi = 0; mi < 4; mi++) {
        #pragma unroll
        for (int ni = 0; ni < 4; ni++) {
            int gcol = col0 + wn + ni * 16 + lr;
            float bb = bias[gcol];
            #pragma unroll
            for (int r = 0; r < 4; r++) {
                int grow = row0 + wm + mi * 16 + lg * 4 + r;
                if (grow < N_NODES)
                    C[(size_t)grow * 256 + gcol] = f2bf(acc[mi][ni][r] + bb);
            }
        }
    }
}

// ---------------------------------------------------------------------------
// Single-block scan, wave-shuffle version: 3 barriers/tile instead of ~22.
// ---------------------------------------------------------------------------
__global__ __launch_bounds__(1024) void scan_deg(
    const int* __restrict__ deg, int* __restrict__ rowptr)
{
    __shared__ int wsum[16];
    __shared__ int wpre[16];
    int t = threadIdx.x;
    int wid = t >> 6, ln = t & 63;
    int carry = 0;
    for (int base = 0; base < N_NODES; base += 4096) {
        int i4 = base + t * 4;
        int4 dv = {0, 0, 0, 0};
        if (i4 < N_NODES) dv = *(const int4*)(deg + i4);  // N_NODES%4==0
        int sum = dv.x + dv.y + dv.z + dv.w;
        int inc = sum;
        #pragma unroll
        for (int off = 1; off < 64; off <<= 1) {
            int u = __shfl_up(inc, off);
            if (ln >= off) inc += u;
        }
        if (ln == 63) wsum[wid] = inc;
        __syncthreads();                       // (1) wsum visible
        if (wid == 0 && ln < 16) {
            int s = wsum[ln];
            int p = s;
            #pragma unroll
            for (int off = 1; off < 16; off <<= 1) {
                int u = __shfl_up(p, off);
                if (ln >= off) p += u;
            }
            wpre[ln] = p - s;                  // exclusive wave prefix
        }
        __syncthreads();                       // (2) wpre visible
        if (i4 < N_NODES) {
            int r = carry + wpre[wid] + (inc - sum);   // exclusive prefix
            r += dv.x; rowptr[i4 + 1] = r;
            r += dv.y; rowptr[i4 + 2] = r;
            r += dv.z; rowptr[i4 + 3] = r;
            r += dv.w; rowptr[i4 + 4] = r;
        }
        carry += wpre[15] + wsum[15];          // block total
        __syncthreads();                       // (3) protect wsum for next tile
    }
    if (t == 0) rowptr[0] = 0;
}

// csr_scatter consumes deg via atomicSub (deg dead after scan).
// Payload is src[e] directly — node_attn then needs NO src[] indirection.
__global__ __launch_bounds__(256) void csr_scatter(
    const int* __restrict__ src, const int* __restrict__ dst,
    const int* __restrict__ rowptr,
    int* __restrict__ deg, int* __restrict__ edge_src)
{
    int e = blockIdx.x * 256 + threadIdx.x;
    if (e >= N_EDGES) return;
    int d = dst[e];
    int old = atomicSub(deg + d, 1);      // old in [1..degree]
    edge_src[rowptr[d] + old - 1] = src[e];
}

// ---------------------------------------------------------------------------
// Fused single-pass attention per dst node. One wave per node, half-wave per
// edge stream (32 lanes x 8 bf16 = 256 dims). Flash-style online softmax in
// exp2/log2 domain.
//
// R2 restructure: wave-uniform COUNTED loop (U = roundup3(ceil(deg/2)) is the
// same for both halves -> scalar s_cbranch, full exec, zero per-iter guard
// chain). All loads unconditional with clamped indices (min(i, end-1) is
// always a valid row); invalid slots neutralized branchlessly (sc -> -1e30,
// w -> 0, alpha = 1 keeps state). Hand-unrolled x3 with 3 rotating register
// buffers: zero pipeline-shift moves; rows loaded 2 bodies ahead, src ids
// fetched 4 slots ahead (2-body slack).
// ---------------------------------------------------------------------------
__global__ __launch_bounds__(256) void node_attn(
    const unsigned short* __restrict__ qbf,
    const unsigned short* __restrict__ kbf,
    const unsigned short* __restrict__ vbf,
    const int* __restrict__ rowptr, const int* __restrict__ edge_src,
    float* __restrict__ out)
{
    int node = blockIdx.x * 4 + (threadIdx.x >> 6);
    int lane = threadIdx.x & 63;
    if (node >= N_NODES) return;
    const int half = lane >> 5;
    const int l = lane & 31;

    int beg = rowptr[node], end = rowptr[node + 1];
    int deg = end - beg;

    float* op = out + (size_t)node * 256 + l * 8;
    if (deg <= 0) {               // no incoming edges -> zeros (matches ref)
        if (half == 0) {
            float4 z4 = {0.f, 0.f, 0.f, 0.f};
            *(float4*)op = z4;
            *(float4*)(op + 4) = z4;
        }
        return;
    }

    f32x2 kf2[4];
    up2x4(*(const uint4*)(kbf + (size_t)node * 256 + l * 8), kf2);

    const unsigned short* qrow = qbf + l * 8;   // + id*256 shorts per edge
    const unsigned short* vrow = vbf + l * 8;

    // 1/sqrt(32) * log2(e): softmax runs in exp2 domain (ratios exact)
    const float SC = 0.17677669529663687f * 1.4426950408889634f;

    int U = (deg + 1) >> 1;            // computes per half (half1 may be -1)
    U = ((U + 2) / 3) * 3;             // round up to unroll factor
    U = __builtin_amdgcn_readfirstlane(U);   // wave-uniform -> scalar loop

    const int i0 = beg + half;         // this half's stream, stride 2
    const int last = end - 1;          // clamp target (valid: deg >= 1)

    // ramp: rows for slots 0,1; ids for slots 2,3 (slot 4 fetched by body0)
    int tmp0 = edge_src[min(i0,     last)];
    int tmp1 = edge_src[min(i0 + 2, last)];
    int idC  = edge_src[min(i0 + 4, last)];
    int idA  = edge_src[min(i0 + 6, last)];
    int idB  = 0;
    uint4 qA = *(const uint4*)(qrow + (size_t)tmp0 * 256);
    uint4 vA = *(const uint4*)(vrow + (size_t)tmp0 * 256);
    uint4 qB = *(const uint4*)(qrow + (size_t)tmp1 * 256);
    uint4 vB = *(const uint4*)(vrow + (size_t)tmp1 * 256);
    uint4 qC, vC;

    float m = -1e30f, zsum = 0.0f;
    f32x2 af2[4] = {};

// body for slot t+P: compute from (QW,VW); load rows of slot t+P+2 into
// (QL,VL) via IDL; fetch id of slot t+P+4 into IDF.
#define BODY(QW, VW, QL, VL, IDL, IDF, P)                                    \
    do {                                                                     \
        size_t off_ = (size_t)(IDL) * 256;                                   \
        QL = *(const uint4*)(qrow + off_);                                   \
        VL = *(const uint4*)(vrow + off_);                                   \
        int vi_ = i0 + 2 * t + 2 * (P);                                      \
        IDF = edge_src[min(vi_ + 8, last)];                                  \
        f32x2 qf_[4], vf_[4];                                                \
        up2x4(QW, qf_);                                                      \
        up2x4(VW, vf_);                                                      \
        f32x2 d_ = qf_[0] * kf2[0];                                          \
        d_ += qf_[1] * kf2[1];                                               \
        d_ += qf_[2] * kf2[2];                                               \
        d_ += qf_[3] * kf2[3];                                               \
        float s_ = d_.x + d_.y;                                              \
        s_ += __shfl_xor(s_, 1);                                             \
        s_ += __shfl_xor(s_, 2);                                             \
        bool ok_ = vi_ < end;                                                \
        float sc_ = ok_ ? s_ * SC : -1e30f;                                  \
        float mn_ = fmaxf(m, sc_);                                           \
        float w_ = exp2f(sc_ - mn_);                                         \
        w_ = ok_ ? w_ : 0.0f;                                                \
        float al_ = exp2f(m - mn_);                                          \
        zsum = zsum * al_ + w_;                                              \
        f32x2 a2_ = {al_, al_}, w2_ = {w_, w_};                              \
        af2[0] = af2[0] * a2_ + vf_[0] * w2_;                                \
        af2[1] = af2[1] * a2_ + vf_[1] * w2_;                                \
        af2[2] = af2[2] * a2_ + vf_[2] * w2_;                                \
        af2[3] = af2[3] * a2_ + vf_[3] * w2_;                                \
        m = mn_;                                                             \
    } while (0)

    for (int t = 0; t < U; t += 3) {
        BODY(qA, vA, qC, vC, idC, idB, 0);
        BODY(qB, vB, qA, vA, idA, idC, 1);
        BODY(qC, vC, qB, vB, idB, idA, 2);
    }
#undef BODY

    // combine halves: rescale to common max, sum across lane^32
    float mo = __shfl_xor(m, 32);
    float mt = fmaxf(m, mo);
    float scale = exp2f(m - mt);       // empty half: exp2(-1e30 - mt) = 0
    zsum *= scale;
    zsum += __shfl_xor(zsum, 32);
    #pragma unroll
    for (int j = 0; j < 4; j++) {
        af2[j].x = af2[j].x * scale;
        af2[j].y = af2[j].y * scale;
        af2[j].x += __shfl_xor(af2[j].x, 32);
        af2[j].y += __shfl_xor(af2[j].y, 32);
    }

    float inv = 1.0f / fmaxf(zsum, 1e-16f);
    if (half == 0) {
        float4 o0 = {af2[0].x * inv, af2[0].y * inv, af2[1].x * inv, af2[1].y * inv};
        float4 o1 = {af2[2].x * inv, af2[2].y * inv, af2[3].x * inv, af2[3].y * inv};
        *(float4*)op = o0;
        *(float4*)(op + 4) = o1;
    }
}

// ---------------------------------------------------------------------------
extern "C" void kernel_launch(void* const* d_in, const int* in_sizes, int n_in,
                              void* d_out, int out_size, void* d_ws, size_t ws_size,
                              hipStream_t stream) {
    const float* x  = (const float*)d_in[0];
    const float* Wq = (const float*)d_in[1];
    const float* bq = (const float*)d_in[2];
    const float* Wk = (const float*)d_in[3];
    const float* bk = (const float*)d_in[4];
    const float* Wv = (const float*)d_in[5];
    const float* bv = (const float*)d_in[6];
    const int* src  = (const int*)d_in[7];
    const int* dst  = (const int*)d_in[8];
    float* out = (float*)d_out;

    unsigned short* qbf = (unsigned short*)d_ws;
    unsigned short* kbf = qbf + (size_t)N_NODES * INNER;
    unsigned short* vbf = kbf + (size_t)N_NODES * INNER;
    unsigned short* xbf = vbf + (size_t)N_NODES * INNER;
    unsigned short* Wt  = xbf + (size_t)M_PAD * INNER;
    int* deg      = (int*)(Wt + 3 * 65536);
    int* rowptr   = deg + N_NODES;
    int* edge_src = rowptr + (N_NODES + 1);

    hipMemsetAsync(deg, 0, (size_t)N_NODES * sizeof(int), stream);

    prep<<<NB_CONVX + NB_CONVW + NB_HIST, 256, 0, stream>>>(
        x, Wq, Wk, Wv, dst, xbf, Wt, deg);

    gemm_qkv<<<GEMM_NWG, 256, 0, stream>>>(xbf, Wt, bq, bk, bv, qbf, kbf, vbf);

    scan_deg<<<1, 1024, 0, stream>>>(deg, rowptr);
    csr_scatter<<<(N_EDGES + 255) / 256, 256, 0, stream>>>(
        src, dst, rowptr, deg, edge_src);

    node_attn<<<(N_NODES + 3) / 4, 256, 0, stream>>>(
        qbf, kbf, vbf, rowptr, edge_src, out);
}